// Round 1
// baseline (1631.901 us; speedup 1.0000x reference)
//
#include <hip/hip_runtime.h>
#include <cstdint>
#include <cstddef>

#define E_ 32
#define TOPK_ 4
#define H_ 1024
#define I_ 1024
#define T_ 2048
#define ALPHA_ 1.702f
#define LIMIT_ 7.0f

// ---------------------------------------------------------------------------
// Kernel 1: router. One block (128 threads) per token.
// Computes 32 logits, top-4, softmax, writes router_scores row, and appends
// (token*4+k, weight) into per-expert buckets via device-scope atomics.
// ---------------------------------------------------------------------------
__global__ __launch_bounds__(128)
void router_kernel(const float* __restrict__ x,
                   const float* __restrict__ rw,
                   const float* __restrict__ rb,
                   float* __restrict__ scores,      // [T][E]
                   int* __restrict__ counts,        // [E]
                   int* __restrict__ tok_list,      // [E][T] encoded t*4+k
                   float* __restrict__ w_list) {    // [E][T]
  int t = blockIdx.x;
  int tid = threadIdx.x;
  __shared__ float partial[128];
  __shared__ float logits[E_];
  int e = tid & 31, q = tid >> 5;          // 4 h-chunks of 256 per expert
  const float* xp = x + (size_t)t * H_;
  const float* wp = rw + (size_t)e * H_ + q * 256;
  float s = 0.f;
  #pragma unroll 8
  for (int h = 0; h < 256; ++h) s += xp[q * 256 + h] * wp[h];
  partial[tid] = s;
  __syncthreads();
  if (tid < 32)
    logits[tid] = partial[tid] + partial[tid + 32] + partial[tid + 64] +
                  partial[tid + 96] + rb[tid];
  __syncthreads();
  if (tid == 0) {
    float l[E_];
    #pragma unroll
    for (int i = 0; i < E_; ++i) l[i] = logits[i];
    int idx[TOPK_]; float v[TOPK_];
    for (int k = 0; k < TOPK_; ++k) {
      int bi = 0; float bv = -1e30f;
      for (int i = 0; i < E_; ++i) {
        if (l[i] > bv) { bv = l[i]; bi = i; }   // strict > : first index on tie
      }
      idx[k] = bi; v[k] = bv; l[bi] = -1e30f;
    }
    float m = v[0], den = 0.f, w[TOPK_];
    for (int k = 0; k < TOPK_; ++k) { w[k] = expf(v[k] - m); den += w[k]; }
    float inv = 1.f / den;
    float* srow = scores + (size_t)t * E_;
    #pragma unroll
    for (int i = 0; i < E_; ++i) srow[i] = 0.f;
    for (int k = 0; k < TOPK_; ++k) {
      float wk = w[k] * inv;
      srow[idx[k]] = wk;
      int pos = atomicAdd(&counts[idx[k]], 1);
      tok_list[idx[k] * T_ + pos] = t * TOPK_ + k;
      w_list[idx[k] * T_ + pos] = wk;
    }
  }
}

// ---------------------------------------------------------------------------
// Kernel 2: gate_up GEMM + activation, per expert.
// Block tile: 64 tokens x 64 i-values (= 128 interleaved weight cols).
// grid = (16 i-tiles, 32 token-tiles, 32 experts); token-tiles past the
// expert's count exit immediately.
// ---------------------------------------------------------------------------
__global__ __launch_bounds__(256)
void gateup_kernel(const float* __restrict__ x,
                   const float* __restrict__ gw,     // [E][H][2I]
                   const float* __restrict__ gb,     // [E][2I]
                   const int* __restrict__ counts,
                   const int* __restrict__ tok_list,
                   float* __restrict__ act_buf) {    // [T*4][I]
  int e = blockIdx.z;
  int cnt = counts[e];
  int t0 = blockIdx.y * 64;
  if (t0 >= cnt) return;
  int itile = blockIdx.x;
  int tid = threadIdx.x;
  int ty = tid >> 4, tx = tid & 15;
  __shared__ float Xs[64][17];      // [token][k] +1 pad: conflict-free
  __shared__ float Ws[16][128];     // [k][col]
  __shared__ int toks[64];
  if (tid < 64) {
    int slot = t0 + tid;
    toks[tid] = (slot < cnt) ? tok_list[e * T_ + slot] : -1;
  }
  __syncthreads();
  float accg[4][4] = {}, accu[4][4] = {};
  const float* wbase = gw + (size_t)e * H_ * (2 * I_) + itile * 128;
  for (int k0 = 0; k0 < H_; k0 += 16) {
    // stage weights: 16 rows x 128 cols, float4, coalesced
    #pragma unroll
    for (int r = 0; r < 2; ++r) {
      int fi = tid + r * 256;
      int kk = fi >> 5, c4 = (fi & 31) * 4;
      float4 wv = *(const float4*)(wbase + (size_t)(k0 + kk) * (2 * I_) + c4);
      *(float4*)&Ws[kk][c4] = wv;
    }
    // gather x rows: 16 contiguous h per 16-lane group
    #pragma unroll
    for (int rep = 0; rep < 4; ++rep) {
      int tt = rep * 16 + (tid >> 4);
      int kk = tid & 15;
      int enc = toks[tt];
      Xs[tt][kk] = (enc >= 0) ? x[(size_t)(enc >> 2) * H_ + k0 + kk] : 0.f;
    }
    __syncthreads();
    #pragma unroll
    for (int kk = 0; kk < 16; ++kk) {
      float xa[4];
      #pragma unroll
      for (int a = 0; a < 4; ++a) xa[a] = Xs[ty + 16 * a][kk];
      #pragma unroll
      for (int b = 0; b < 4; ++b) {
        float2 wv = *(const float2*)&Ws[kk][2 * (tx + 16 * b)];
        #pragma unroll
        for (int a = 0; a < 4; ++a) {
          accg[a][b] = fmaf(xa[a], wv.x, accg[a][b]);
          accu[a][b] = fmaf(xa[a], wv.y, accu[a][b]);
        }
      }
    }
    __syncthreads();
  }
  // epilogue: bias + clamp + glu, store act
  #pragma unroll
  for (int b = 0; b < 4; ++b) {
    int i = itile * 64 + tx + 16 * b;
    float bg = gb[e * (2 * I_) + 2 * i];
    float bu = gb[e * (2 * I_) + 2 * i + 1];
    #pragma unroll
    for (int a = 0; a < 4; ++a) {
      int tt = ty + 16 * a;
      int enc = toks[tt];
      if (enc < 0) continue;
      float g = accg[a][b] + bg;
      float u = accu[a][b] + bu;
      g = fminf(g, LIMIT_);
      u = fminf(fmaxf(u, -LIMIT_), LIMIT_);
      float glu = g / (1.f + expf(-ALPHA_ * g));
      act_buf[(size_t)enc * I_ + i] = (u + 1.f) * glu;
    }
  }
}

// ---------------------------------------------------------------------------
// Kernel 3: down GEMM, per expert, scaled by router weight, atomicAdd scatter.
// Block tile: 64 tokens x 64 h. grid = (16 h-tiles, 32 token-tiles, 32 experts)
// ---------------------------------------------------------------------------
__global__ __launch_bounds__(256)
void down_kernel(const float* __restrict__ act_buf,
                 const float* __restrict__ dw,       // [E][I][H]
                 const float* __restrict__ db,       // [E][H]
                 const int* __restrict__ counts,
                 const int* __restrict__ tok_list,
                 const float* __restrict__ w_list,
                 float* __restrict__ routed) {       // [T][H], pre-zeroed
  int e = blockIdx.z;
  int cnt = counts[e];
  int t0 = blockIdx.y * 64;
  if (t0 >= cnt) return;
  int htile = blockIdx.x;
  int tid = threadIdx.x;
  int ty = tid >> 4, tx = tid & 15;
  __shared__ float As[64][17];
  __shared__ float Wd[16][64];
  __shared__ int toks[64];
  __shared__ float tws[64];
  if (tid < 64) {
    int slot = t0 + tid;
    bool ok = slot < cnt;
    toks[tid] = ok ? tok_list[e * T_ + slot] : -1;
    tws[tid] = ok ? w_list[e * T_ + slot] : 0.f;
  }
  __syncthreads();
  float acc[4][4] = {};
  const float* wbase = dw + (size_t)e * I_ * H_ + htile * 64;
  for (int k0 = 0; k0 < I_; k0 += 16) {
    {
      int kk = tid >> 4;
      int c4 = (tid & 15) * 4;
      float4 wv = *(const float4*)(wbase + (size_t)(k0 + kk) * H_ + c4);
      *(float4*)&Wd[kk][c4] = wv;
    }
    #pragma unroll
    for (int rep = 0; rep < 4; ++rep) {
      int tt = rep * 16 + (tid >> 4);
      int kk = tid & 15;
      int enc = toks[tt];
      As[tt][kk] = (enc >= 0) ? act_buf[(size_t)enc * I_ + k0 + kk] : 0.f;
    }
    __syncthreads();
    #pragma unroll
    for (int kk = 0; kk < 16; ++kk) {
      float av[4];
      #pragma unroll
      for (int a = 0; a < 4; ++a) av[a] = As[ty + 16 * a][kk];
      #pragma unroll
      for (int b = 0; b < 4; ++b) {
        float wv = Wd[kk][tx + 16 * b];
        #pragma unroll
        for (int a = 0; a < 4; ++a) acc[a][b] = fmaf(av[a], wv, acc[a][b]);
      }
    }
    __syncthreads();
  }
  #pragma unroll
  for (int b = 0; b < 4; ++b) {
    int h = htile * 64 + tx + 16 * b;
    float bias = db[e * H_ + h];
    #pragma unroll
    for (int a = 0; a < 4; ++a) {
      int tt = ty + 16 * a;
      int enc = toks[tt];
      if (enc < 0) continue;
      int t = enc >> 2;
      atomicAdd(&routed[(size_t)t * H_ + h], tws[tt] * (acc[a][b] + bias));
    }
  }
}

// ---------------------------------------------------------------------------
extern "C" void kernel_launch(void* const* d_in, const int* in_sizes, int n_in,
                              void* d_out, int out_size, void* d_ws, size_t ws_size,
                              hipStream_t stream) {
  (void)in_sizes; (void)n_in; (void)out_size; (void)ws_size;
  const float* x    = (const float*)d_in[0];   // [T][H]
  const float* gup  = (const float*)d_in[1];   // [E][H][2I]
  const float* gupb = (const float*)d_in[2];   // [E][2I]
  const float* dwn  = (const float*)d_in[3];   // [E][I][H]
  const float* dwnb = (const float*)d_in[4];   // [E][H]
  const float* rw   = (const float*)d_in[5];   // [E][H]
  const float* rb   = (const float*)d_in[6];   // [E]

  float* routed = (float*)d_out;                         // [T][H]
  float* scores = (float*)d_out + (size_t)T_ * H_;       // [T][E]

  char* ws = (char*)d_ws;
  int*   counts   = (int*)ws;                                    // 32 ints
  int*   tok_list = (int*)(ws + 256);                            // E*T ints
  float* w_list   = (float*)(ws + 256 + (size_t)E_ * T_ * 4);    // E*T floats
  float* act_buf  = (float*)(ws + 256 + 2 * (size_t)E_ * T_ * 4);// T*4*I floats (33.5 MB)

  hipMemsetAsync(counts, 0, E_ * sizeof(int), stream);
  hipMemsetAsync(routed, 0, (size_t)T_ * H_ * sizeof(float), stream);

  router_kernel<<<T_, 128, 0, stream>>>(x, rw, rb, scores, counts, tok_list, w_list);
  gateup_kernel<<<dim3(16, 32, 32), 256, 0, stream>>>(x, gup, gupb, counts, tok_list, act_buf);
  down_kernel<<<dim3(16, 32, 32), 256, 0, stream>>>(act_buf, dwn, dwnb, counts, tok_list, w_list, routed);
}

// Round 2
// 682.721 us; speedup vs baseline: 2.3903x; 2.3903x over previous
//
#include <hip/hip_runtime.h>
#include <cstdint>
#include <cstddef>

#define E_ 32
#define TOPK_ 4
#define H_ 1024
#define I_ 1024
#define T_ 2048
#define ALPHA_ 1.702f
#define LIMIT_ 7.0f
#define BK_ 32          // K-chunk per MFMA stage
#define BKP_ 40         // padded LDS row (bf16 elems): 80 B -> 2-way bank alias = free

typedef __attribute__((ext_vector_type(8))) short s8;   // 8 bf16 = one MFMA operand frag
typedef __attribute__((ext_vector_type(4))) float f4;   // MFMA accumulator

// fp32 -> bf16 round-to-nearest-even (no NaN care needed here)
__device__ __forceinline__ unsigned short f2bf(float f) {
  unsigned int u = __float_as_uint(f);
  return (unsigned short)((u + 0x7fffu + ((u >> 16) & 1u)) >> 16);
}

// ---------------------------------------------------------------------------
// Kernel 1: router (unchanged from R1 — correct, small fraction of runtime).
// ---------------------------------------------------------------------------
__global__ __launch_bounds__(128)
void router_kernel(const float* __restrict__ x,
                   const float* __restrict__ rw,
                   const float* __restrict__ rb,
                   float* __restrict__ scores,
                   int* __restrict__ counts,
                   int* __restrict__ tok_list,
                   float* __restrict__ w_list) {
  int t = blockIdx.x;
  int tid = threadIdx.x;
  __shared__ float partial[128];
  __shared__ float logits[E_];
  int e = tid & 31, q = tid >> 5;
  const float* xp = x + (size_t)t * H_;
  const float* wp = rw + (size_t)e * H_ + q * 256;
  float s = 0.f;
  #pragma unroll 8
  for (int h = 0; h < 256; ++h) s += xp[q * 256 + h] * wp[h];
  partial[tid] = s;
  __syncthreads();
  if (tid < 32)
    logits[tid] = partial[tid] + partial[tid + 32] + partial[tid + 64] +
                  partial[tid + 96] + rb[tid];
  __syncthreads();
  if (tid == 0) {
    float l[E_];
    #pragma unroll
    for (int i = 0; i < E_; ++i) l[i] = logits[i];
    int idx[TOPK_]; float v[TOPK_];
    for (int k = 0; k < TOPK_; ++k) {
      int bi = 0; float bv = -1e30f;
      for (int i = 0; i < E_; ++i)
        if (l[i] > bv) { bv = l[i]; bi = i; }
      idx[k] = bi; v[k] = bv; l[bi] = -1e30f;
    }
    float m = v[0], den = 0.f, w[TOPK_];
    for (int k = 0; k < TOPK_; ++k) { w[k] = expf(v[k] - m); den += w[k]; }
    float inv = 1.f / den;
    float* srow = scores + (size_t)t * E_;
    #pragma unroll
    for (int i = 0; i < E_; ++i) srow[i] = 0.f;
    for (int k = 0; k < TOPK_; ++k) {
      float wk = w[k] * inv;
      srow[idx[k]] = wk;
      int pos = atomicAdd(&counts[idx[k]], 1);
      tok_list[idx[k] * T_ + pos] = t * TOPK_ + k;
      w_list[idx[k] * T_ + pos] = wk;
    }
  }
}

// ---------------------------------------------------------------------------
// Kernel 2: gate_up via bf16 MFMA. Block = 64 tokens x 64 i (128 weight cols).
// Weights fp32 [K][2I] are transposed+converted into LDS [col][k] during
// staging; gate (even) cols land in rows 0..63, up (odd) in rows 64..127, so
// each lane's D fragment holds matching (gate,up) pairs -> no shuffle epilogue.
// ---------------------------------------------------------------------------
__global__ __launch_bounds__(256)
void gateup_mfma(const float* __restrict__ x,
                 const float* __restrict__ gw,     // [E][H][2I]
                 const float* __restrict__ gb,     // [E][2I]
                 const int* __restrict__ counts,
                 const int* __restrict__ tok_list,
                 unsigned short* __restrict__ act) { // [T*4][I] bf16
  int e = blockIdx.z;
  int cnt = counts[e];
  int t0 = blockIdx.y * 64;
  if (t0 >= cnt) return;
  int itile = blockIdx.x;
  int tid = threadIdx.x;
  int lane = tid & 63;
  int wave = tid >> 6;
  int wm = wave >> 1, wn = wave & 1;

  __shared__ __align__(16) unsigned short Xs[64][BKP_];
  __shared__ __align__(16) unsigned short Wg[128][BKP_];
  __shared__ int toks[64];

  if (tid < 64) {
    int slot = t0 + tid;
    toks[tid] = (slot < cnt) ? tok_list[e * T_ + slot] : -1;
  }
  __syncthreads();

  f4 accg[2][2] = {};
  f4 accu[2][2] = {};

  int arow = tid >> 2;
  int akq  = (tid & 3) * 8;
  int aenc = toks[arow];
  const float* axp = (aenc >= 0) ? (x + (size_t)(aenc >> 2) * H_) : x;
  const float* wbase = gw + (size_t)e * H_ * (2 * I_) + itile * 128;

  int fm = lane & 15, ko = (lane >> 4) * 8;

  for (int k0 = 0; k0 < H_; k0 += BK_) {
    // --- stage A: 64x32 tokens, fp32 -> bf16 ---
    s8 av = {};
    if (aenc >= 0) {
      float4 p0 = *(const float4*)(axp + k0 + akq);
      float4 p1 = *(const float4*)(axp + k0 + akq + 4);
      av[0] = (short)f2bf(p0.x); av[1] = (short)f2bf(p0.y);
      av[2] = (short)f2bf(p0.z); av[3] = (short)f2bf(p0.w);
      av[4] = (short)f2bf(p1.x); av[5] = (short)f2bf(p1.y);
      av[6] = (short)f2bf(p1.z); av[7] = (short)f2bf(p1.w);
    }
    *(s8*)&Xs[arow][akq] = av;
    // --- stage B: 32x128, transpose to [col][k] + deinterleave gate/up ---
    #pragma unroll
    for (int r = 0; r < 2; ++r) {
      int tau = tid + r * 256;
      int n = tau & 127, koct = tau >> 7;
      const float* wp = wbase + (size_t)(k0 + koct * 8) * (2 * I_) + n;
      s8 bv;
      #pragma unroll
      for (int j = 0; j < 8; ++j)
        bv[j] = (short)f2bf(wp[(size_t)j * (2 * I_)]);
      int drow = (n >> 1) + (n & 1) * 64;
      *(s8*)&Wg[drow][koct * 8] = bv;
    }
    __syncthreads();
    // --- MFMA: wave tile 32 tokens x 32 i (gate + up) ---
    s8 a0 = *(s8*)&Xs[wm * 32 + fm][ko];
    s8 a1 = *(s8*)&Xs[wm * 32 + 16 + fm][ko];
    #pragma unroll
    for (int g = 0; g < 2; ++g) {
      s8 bg = *(s8*)&Wg[wn * 32 + g * 16 + fm][ko];
      s8 bu = *(s8*)&Wg[64 + wn * 32 + g * 16 + fm][ko];
      accg[0][g] = __builtin_amdgcn_mfma_f32_16x16x32_bf16(a0, bg, accg[0][g], 0, 0, 0);
      accg[1][g] = __builtin_amdgcn_mfma_f32_16x16x32_bf16(a1, bg, accg[1][g], 0, 0, 0);
      accu[0][g] = __builtin_amdgcn_mfma_f32_16x16x32_bf16(a0, bu, accu[0][g], 0, 0, 0);
      accu[1][g] = __builtin_amdgcn_mfma_f32_16x16x32_bf16(a1, bu, accu[1][g], 0, 0, 0);
    }
    __syncthreads();
  }

  // --- epilogue: bias + clamp + glu, store bf16 act ---
  int rq = lane >> 4;
  #pragma unroll
  for (int g = 0; g < 2; ++g) {
    int i = itile * 64 + wn * 32 + g * 16 + (lane & 15);
    float bg_ = gb[e * 2 * I_ + 2 * i];
    float bu_ = gb[e * 2 * I_ + 2 * i + 1];
    #pragma unroll
    for (int f = 0; f < 2; ++f) {
      #pragma unroll
      for (int r = 0; r < 4; ++r) {
        int m = wm * 32 + f * 16 + rq * 4 + r;
        int enc = toks[m];
        if (enc < 0) continue;
        float gv = accg[f][g][r] + bg_;
        float uv = accu[f][g][r] + bu_;
        gv = fminf(gv, LIMIT_);
        uv = fminf(fmaxf(uv, -LIMIT_), LIMIT_);
        float glu = gv / (1.f + __expf(-ALPHA_ * gv));
        act[(size_t)enc * I_ + i] = f2bf((uv + 1.f) * glu);
      }
    }
  }
}

// ---------------------------------------------------------------------------
// Kernel 3: down-proj via bf16 MFMA. Block = 64 tokens x 128 h.
// Writes per-assignment fp32 rows dsout[enc][h] (router weight applied);
// no atomics — combine kernel sums the 4 rows per token.
// ---------------------------------------------------------------------------
__global__ __launch_bounds__(256)
void down_mfma(const unsigned short* __restrict__ act,  // [T*4][I] bf16
               const float* __restrict__ dw,            // [E][I][H]
               const float* __restrict__ db,            // [E][H]
               const int* __restrict__ counts,
               const int* __restrict__ tok_list,
               const float* __restrict__ w_list,
               float* __restrict__ dsout) {             // [T*4][H] fp32
  int e = blockIdx.z;
  int cnt = counts[e];
  int t0 = blockIdx.y * 64;
  if (t0 >= cnt) return;
  int htile = blockIdx.x;
  int tid = threadIdx.x;
  int lane = tid & 63;
  int wave = tid >> 6;
  int wm = wave >> 1, wn = wave & 1;

  __shared__ __align__(16) unsigned short Xs[64][BKP_];
  __shared__ __align__(16) unsigned short Wd[128][BKP_];
  __shared__ int toks[64];
  __shared__ float tws[64];

  if (tid < 64) {
    int slot = t0 + tid;
    bool ok = slot < cnt;
    toks[tid] = ok ? tok_list[e * T_ + slot] : -1;
    tws[tid]  = ok ? w_list[e * T_ + slot] : 0.f;
  }
  __syncthreads();

  f4 acc[2][4] = {};

  int arow = tid >> 2;
  int akq  = (tid & 3) * 8;
  int aenc = toks[arow];
  const unsigned short* axp = (aenc >= 0) ? (act + (size_t)aenc * I_) : act;
  const float* wbase = dw + (size_t)e * I_ * H_ + htile * 128;

  int fm = lane & 15, ko = (lane >> 4) * 8;

  for (int k0 = 0; k0 < I_; k0 += BK_) {
    s8 av = {};
    if (aenc >= 0) av = *(const s8*)(axp + k0 + akq);
    *(s8*)&Xs[arow][akq] = av;
    #pragma unroll
    for (int r = 0; r < 2; ++r) {
      int tau = tid + r * 256;
      int n = tau & 127, koct = tau >> 7;
      const float* wp = wbase + (size_t)(k0 + koct * 8) * H_ + n;
      s8 bv;
      #pragma unroll
      for (int j = 0; j < 8; ++j)
        bv[j] = (short)f2bf(wp[(size_t)j * H_]);
      *(s8*)&Wd[n][koct * 8] = bv;
    }
    __syncthreads();
    s8 a0 = *(s8*)&Xs[wm * 32 + fm][ko];
    s8 a1 = *(s8*)&Xs[wm * 32 + 16 + fm][ko];
    #pragma unroll
    for (int g = 0; g < 4; ++g) {
      s8 b = *(s8*)&Wd[wn * 64 + g * 16 + fm][ko];
      acc[0][g] = __builtin_amdgcn_mfma_f32_16x16x32_bf16(a0, b, acc[0][g], 0, 0, 0);
      acc[1][g] = __builtin_amdgcn_mfma_f32_16x16x32_bf16(a1, b, acc[1][g], 0, 0, 0);
    }
    __syncthreads();
  }

  int rq = lane >> 4;
  #pragma unroll
  for (int g = 0; g < 4; ++g) {
    int h = htile * 128 + wn * 64 + g * 16 + (lane & 15);
    float bias = db[e * H_ + h];
    #pragma unroll
    for (int f = 0; f < 2; ++f) {
      #pragma unroll
      for (int r = 0; r < 4; ++r) {
        int m = wm * 32 + f * 16 + rq * 4 + r;
        int enc = toks[m];
        if (enc < 0) continue;
        dsout[(size_t)enc * H_ + h] = (acc[f][g][r] + bias) * tws[m];
      }
    }
  }
}

// ---------------------------------------------------------------------------
// Kernel 4: combine — out[t][h] = sum_k dsout[t*4+k][h]. Fully coalesced.
// ---------------------------------------------------------------------------
__global__ __launch_bounds__(256)
void combine_kernel(const float* __restrict__ dsout,
                    float* __restrict__ routed) {
  int idx = blockIdx.x * 256 + threadIdx.x;   // one float4 group
  int t = idx >> 8;                           // H/4 = 256 groups per token
  int h = (idx & 255) * 4;
  const float* base = dsout + (size_t)t * 4 * H_ + h;
  float4 a = *(const float4*)(base);
  float4 b = *(const float4*)(base + H_);
  float4 c = *(const float4*)(base + 2 * H_);
  float4 d = *(const float4*)(base + 3 * H_);
  float4 o;
  o.x = a.x + b.x + c.x + d.x;
  o.y = a.y + b.y + c.y + d.y;
  o.z = a.z + b.z + c.z + d.z;
  o.w = a.w + b.w + c.w + d.w;
  *(float4*)(routed + (size_t)t * H_ + h) = o;
}

// ---------------------------------------------------------------------------
extern "C" void kernel_launch(void* const* d_in, const int* in_sizes, int n_in,
                              void* d_out, int out_size, void* d_ws, size_t ws_size,
                              hipStream_t stream) {
  (void)in_sizes; (void)n_in; (void)out_size; (void)ws_size;
  const float* x    = (const float*)d_in[0];
  const float* gup  = (const float*)d_in[1];
  const float* gupb = (const float*)d_in[2];
  const float* dwn  = (const float*)d_in[3];
  const float* dwnb = (const float*)d_in[4];
  const float* rw   = (const float*)d_in[5];
  const float* rb   = (const float*)d_in[6];

  float* routed = (float*)d_out;                       // [T][H]
  float* scores = (float*)d_out + (size_t)T_ * H_;     // [T][E]

  char* ws = (char*)d_ws;
  int*   counts   = (int*)ws;                                       // 256 B
  int*   tok_list = (int*)(ws + 256);                               // 256 KB
  float* w_list   = (float*)(ws + 256 + (size_t)E_ * T_ * 4);       // 256 KB
  unsigned short* act = (unsigned short*)(ws + 256 + 2 * (size_t)E_ * T_ * 4); // 16.8 MB bf16
  float* dsout = (float*)(ws + 256 + 2 * (size_t)E_ * T_ * 4
                          + (size_t)T_ * TOPK_ * I_ * 2);           // 33.6 MB fp32

  hipMemsetAsync(counts, 0, E_ * sizeof(int), stream);

  router_kernel<<<T_, 128, 0, stream>>>(x, rw, rb, scores, counts, tok_list, w_list);
  gateup_mfma<<<dim3(16, 32, 32), 256, 0, stream>>>(x, gup, gupb, counts, tok_list, act);
  down_mfma<<<dim3(8, 32, 32), 256, 0, stream>>>(act, dwn, dwnb, counts, tok_list, w_list, dsout);
  combine_kernel<<<(T_ * H_ / 4) / 256, 256, 0, stream>>>(dsout, routed);
}

// Round 4
// 676.957 us; speedup vs baseline: 2.4106x; 1.0085x over previous
//
#include <hip/hip_runtime.h>
#include <cstdint>
#include <cstddef>

#define E_ 32
#define TOPK_ 4
#define H_ 1024
#define I_ 1024
#define T_ 2048
#define ALPHA_ 1.702f
#define LIMIT_ 7.0f
#define BK_ 32
#define BKP_ 40   // padded LDS row (bf16): 80 B -> worst 2-way bank alias = free

typedef __attribute__((ext_vector_type(8))) short s8;
typedef __attribute__((ext_vector_type(4))) float f4;

__device__ __forceinline__ unsigned short f2bf(float f) {
  unsigned int u = __float_as_uint(f);
  return (unsigned short)((u + 0x7fffu + ((u >> 16) & 1u)) >> 16);
}

// ---------------------------------------------------------------------------
// Kernel 1: router (unchanged).
// ---------------------------------------------------------------------------
__global__ __launch_bounds__(128)
void router_kernel(const float* __restrict__ x,
                   const float* __restrict__ rw,
                   const float* __restrict__ rb,
                   float* __restrict__ scores,
                   int* __restrict__ counts,
                   int* __restrict__ tok_list,
                   float* __restrict__ w_list) {
  int t = blockIdx.x;
  int tid = threadIdx.x;
  __shared__ float partial[128];
  __shared__ float logits[E_];
  int e = tid & 31, q = tid >> 5;
  const float* xp = x + (size_t)t * H_;
  const float* wp = rw + (size_t)e * H_ + q * 256;
  float s = 0.f;
  #pragma unroll 8
  for (int h = 0; h < 256; ++h) s += xp[q * 256 + h] * wp[h];
  partial[tid] = s;
  __syncthreads();
  if (tid < 32)
    logits[tid] = partial[tid] + partial[tid + 32] + partial[tid + 64] +
                  partial[tid + 96] + rb[tid];
  __syncthreads();
  if (tid == 0) {
    float l[E_];
    #pragma unroll
    for (int i = 0; i < E_; ++i) l[i] = logits[i];
    int idx[TOPK_]; float v[TOPK_];
    for (int k = 0; k < TOPK_; ++k) {
      int bi = 0; float bv = -1e30f;
      for (int i = 0; i < E_; ++i)
        if (l[i] > bv) { bv = l[i]; bi = i; }
      idx[k] = bi; v[k] = bv; l[bi] = -1e30f;
    }
    float m = v[0], den = 0.f, w[TOPK_];
    for (int k = 0; k < TOPK_; ++k) { w[k] = expf(v[k] - m); den += w[k]; }
    float inv = 1.f / den;
    float* srow = scores + (size_t)t * E_;
    #pragma unroll
    for (int i = 0; i < E_; ++i) srow[i] = 0.f;
    for (int k = 0; k < TOPK_; ++k) {
      float wk = w[k] * inv;
      srow[idx[k]] = wk;
      int pos = atomicAdd(&counts[idx[k]], 1);
      tok_list[idx[k] * T_ + pos] = t * TOPK_ + k;
      w_list[idx[k] * T_ + pos] = wk;
    }
  }
}

// ---------------------------------------------------------------------------
// Kernel 2: gate_up, bf16 MFMA, double-buffered LDS, 1 barrier / K-chunk.
// Block = 64 tokens x 64 i (128 interleaved cols). Register prefetch of the
// next chunk's A (8 fp32) and B (2x8 fp32) overlaps the MFMA phase.
// B staging: thread covers (n0, koct0) and (n0, koct0+2), koct0 = tid>>7.
// ---------------------------------------------------------------------------
__global__ __launch_bounds__(256)
void gateup_mfma(const float* __restrict__ x,
                 const float* __restrict__ gw,     // [E][H][2I]
                 const float* __restrict__ gb,     // [E][2I]
                 const int* __restrict__ counts,
                 const int* __restrict__ tok_list,
                 unsigned short* __restrict__ act) { // [T*4][I] bf16
  int e = blockIdx.z;
  int cnt = counts[e];
  int t0 = blockIdx.y * 64;
  if (t0 >= cnt) return;
  int itile = blockIdx.x;
  int tid = threadIdx.x;
  int lane = tid & 63;
  int wave = tid >> 6;
  int wm = wave >> 1, wn = wave & 1;

  __shared__ __align__(16) unsigned short Xs[2][64][BKP_];
  __shared__ __align__(16) unsigned short Wg[2][128][BKP_];
  __shared__ int toks[64];

  if (tid < 64) {
    int slot = t0 + tid;
    toks[tid] = (slot < cnt) ? tok_list[e * T_ + slot] : -1;
  }
  __syncthreads();

  f4 accg[2][2] = {};
  f4 accu[2][2] = {};

  // A staging: 256 threads cover 64 rows x 32 k (8 fp32 each)
  int arow = tid >> 2;
  int akq  = (tid & 3) * 8;
  int aenc = toks[arow];
  const float* axp = (aenc >= 0) ? (x + (size_t)(aenc >> 2) * H_ + akq) : nullptr;
  // B staging: (n0, koct0) and (n0, koct0+2); koct in {0,1,2,3} covers k0..k0+31
  const float* wbase = gw + (size_t)e * H_ * (2 * I_) + itile * 128;
  int n0 = tid & 127, koct0 = tid >> 7;
  int drow0 = (n0 >> 1) + (n0 & 1) * 64;        // deinterleave gate/up
  const float* wp0 = wbase + (size_t)koct0 * 8 * (2 * I_) + n0;

  int fm = lane & 15, ko = (lane >> 4) * 8;

  float pA[8];
  float pB[2][8];

  // prefetch chunk 0
  {
    if (aenc >= 0) {
      float4 q0 = *(const float4*)(axp);
      float4 q1 = *(const float4*)(axp + 4);
      pA[0]=q0.x; pA[1]=q0.y; pA[2]=q0.z; pA[3]=q0.w;
      pA[4]=q1.x; pA[5]=q1.y; pA[6]=q1.z; pA[7]=q1.w;
    }
    #pragma unroll
    for (int r = 0; r < 2; ++r) {
      const float* wp = wp0 + (size_t)r * 16 * (2 * I_);   // koct += 2
      #pragma unroll
      for (int j = 0; j < 8; ++j) pB[r][j] = wp[(size_t)j * (2 * I_)];
    }
  }

  int buf = 0;
  for (int c = 0; c < H_ / BK_; ++c) {
    // ---- write prefetched chunk c into LDS[buf] ----
    {
      s8 av = {};
      if (aenc >= 0) {
        #pragma unroll
        for (int j = 0; j < 8; ++j) av[j] = (short)f2bf(pA[j]);
      }
      *(s8*)&Xs[buf][arow][akq] = av;
      #pragma unroll
      for (int r = 0; r < 2; ++r) {
        s8 bv;
        #pragma unroll
        for (int j = 0; j < 8; ++j) bv[j] = (short)f2bf(pB[r][j]);
        *(s8*)&Wg[buf][drow0][(koct0 + r * 2) * 8] = bv;
      }
    }
    __syncthreads();
    // ---- issue global loads for chunk c+1 (overlap MFMA below) ----
    if (c + 1 < H_ / BK_) {
      int k0 = (c + 1) * BK_;
      if (aenc >= 0) {
        float4 q0 = *(const float4*)(axp + k0);
        float4 q1 = *(const float4*)(axp + k0 + 4);
        pA[0]=q0.x; pA[1]=q0.y; pA[2]=q0.z; pA[3]=q0.w;
        pA[4]=q1.x; pA[5]=q1.y; pA[6]=q1.z; pA[7]=q1.w;
      }
      #pragma unroll
      for (int r = 0; r < 2; ++r) {
        const float* wp = wp0 + (size_t)(k0 + r * 16) * (2 * I_);
        #pragma unroll
        for (int j = 0; j < 8; ++j) pB[r][j] = wp[(size_t)j * (2 * I_)];
      }
    }
    // ---- MFMA on chunk c ----
    {
      s8 a0 = *(s8*)&Xs[buf][wm * 32 + fm][ko];
      s8 a1 = *(s8*)&Xs[buf][wm * 32 + 16 + fm][ko];
      #pragma unroll
      for (int g = 0; g < 2; ++g) {
        s8 bg = *(s8*)&Wg[buf][wn * 32 + g * 16 + fm][ko];
        s8 bu = *(s8*)&Wg[buf][64 + wn * 32 + g * 16 + fm][ko];
        accg[0][g] = __builtin_amdgcn_mfma_f32_16x16x32_bf16(a0, bg, accg[0][g], 0, 0, 0);
        accg[1][g] = __builtin_amdgcn_mfma_f32_16x16x32_bf16(a1, bg, accg[1][g], 0, 0, 0);
        accu[0][g] = __builtin_amdgcn_mfma_f32_16x16x32_bf16(a0, bu, accu[0][g], 0, 0, 0);
        accu[1][g] = __builtin_amdgcn_mfma_f32_16x16x32_bf16(a1, bu, accu[1][g], 0, 0, 0);
      }
    }
    buf ^= 1;
  }

  int rq = lane >> 4;
  #pragma unroll
  for (int g = 0; g < 2; ++g) {
    int i = itile * 64 + wn * 32 + g * 16 + (lane & 15);
    float bg_ = gb[e * 2 * I_ + 2 * i];
    float bu_ = gb[e * 2 * I_ + 2 * i + 1];
    #pragma unroll
    for (int f = 0; f < 2; ++f) {
      #pragma unroll
      for (int r = 0; r < 4; ++r) {
        int m = wm * 32 + f * 16 + rq * 4 + r;
        int enc = toks[m];
        if (enc < 0) continue;
        float gv = accg[f][g][r] + bg_;
        float uv = accu[f][g][r] + bu_;
        gv = fminf(gv, LIMIT_);
        uv = fminf(fmaxf(uv, -LIMIT_), LIMIT_);
        float glu = gv / (1.f + __expf(-ALPHA_ * gv));
        act[(size_t)enc * I_ + i] = f2bf((uv + 1.f) * glu);
      }
    }
  }
}

// ---------------------------------------------------------------------------
// Kernel 3: down-proj, bf16 MFMA, same pipeline. Block = 64 tokens x 128 h.
// ---------------------------------------------------------------------------
__global__ __launch_bounds__(256)
void down_mfma(const unsigned short* __restrict__ act,  // [T*4][I] bf16
               const float* __restrict__ dw,            // [E][I][H]
               const float* __restrict__ db,            // [E][H]
               const int* __restrict__ counts,
               const int* __restrict__ tok_list,
               const float* __restrict__ w_list,
               float* __restrict__ dsout) {             // [T*4][H] fp32
  int e = blockIdx.z;
  int cnt = counts[e];
  int t0 = blockIdx.y * 64;
  if (t0 >= cnt) return;
  int htile = blockIdx.x;
  int tid = threadIdx.x;
  int lane = tid & 63;
  int wave = tid >> 6;
  int wm = wave >> 1, wn = wave & 1;

  __shared__ __align__(16) unsigned short Xs[2][64][BKP_];
  __shared__ __align__(16) unsigned short Wd[2][128][BKP_];
  __shared__ int toks[64];
  __shared__ float tws[64];

  if (tid < 64) {
    int slot = t0 + tid;
    bool ok = slot < cnt;
    toks[tid] = ok ? tok_list[e * T_ + slot] : -1;
    tws[tid]  = ok ? w_list[e * T_ + slot] : 0.f;
  }
  __syncthreads();

  f4 acc[2][4] = {};

  int arow = tid >> 2;
  int akq  = (tid & 3) * 8;
  int aenc = toks[arow];
  const unsigned short* axp = (aenc >= 0) ? (act + (size_t)aenc * I_ + akq) : nullptr;
  const float* wbase = dw + (size_t)e * I_ * H_ + htile * 128;
  int n0 = tid & 127, koct0 = tid >> 7;
  const float* wp0 = wbase + (size_t)koct0 * 8 * H_ + n0;

  int fm = lane & 15, ko = (lane >> 4) * 8;

  s8 pA = {};
  float pB[2][8];

  {
    if (aenc >= 0) pA = *(const s8*)(axp);
    #pragma unroll
    for (int r = 0; r < 2; ++r) {
      const float* wp = wp0 + (size_t)r * 16 * H_;       // koct += 2
      #pragma unroll
      for (int j = 0; j < 8; ++j) pB[r][j] = wp[(size_t)j * H_];
    }
  }

  int buf = 0;
  for (int c = 0; c < I_ / BK_; ++c) {
    *(s8*)&Xs[buf][arow][akq] = pA;
    #pragma unroll
    for (int r = 0; r < 2; ++r) {
      s8 bv;
      #pragma unroll
      for (int j = 0; j < 8; ++j) bv[j] = (short)f2bf(pB[r][j]);
      *(s8*)&Wd[buf][n0][(koct0 + r * 2) * 8] = bv;
    }
    __syncthreads();
    if (c + 1 < I_ / BK_) {
      int k0 = (c + 1) * BK_;
      if (aenc >= 0) pA = *(const s8*)(axp + k0);
      #pragma unroll
      for (int r = 0; r < 2; ++r) {
        const float* wp = wp0 + (size_t)(k0 + r * 16) * H_;
        #pragma unroll
        for (int j = 0; j < 8; ++j) pB[r][j] = wp[(size_t)j * H_];
      }
    }
    {
      s8 a0 = *(s8*)&Xs[buf][wm * 32 + fm][ko];
      s8 a1 = *(s8*)&Xs[buf][wm * 32 + 16 + fm][ko];
      #pragma unroll
      for (int g = 0; g < 4; ++g) {
        s8 b = *(s8*)&Wd[buf][wn * 64 + g * 16 + fm][ko];
        acc[0][g] = __builtin_amdgcn_mfma_f32_16x16x32_bf16(a0, b, acc[0][g], 0, 0, 0);
        acc[1][g] = __builtin_amdgcn_mfma_f32_16x16x32_bf16(a1, b, acc[1][g], 0, 0, 0);
      }
    }
    buf ^= 1;
  }

  int rq = lane >> 4;
  #pragma unroll
  for (int g = 0; g < 4; ++g) {
    int h = htile * 128 + wn * 64 + g * 16 + (lane & 15);
    float bias = db[e * H_ + h];
    #pragma unroll
    for (int f = 0; f < 2; ++f) {
      #pragma unroll
      for (int r = 0; r < 4; ++r) {
        int m = wm * 32 + f * 16 + rq * 4 + r;
        int enc = toks[m];
        if (enc < 0) continue;
        dsout[(size_t)enc * H_ + h] = (acc[f][g][r] + bias) * tws[m];
      }
    }
  }
}

// ---------------------------------------------------------------------------
// Kernel 4: combine — out[t][h] = sum_k dsout[t*4+k][h].
// ---------------------------------------------------------------------------
__global__ __launch_bounds__(256)
void combine_kernel(const float* __restrict__ dsout,
                    float* __restrict__ routed) {
  int idx = blockIdx.x * 256 + threadIdx.x;
  int t = idx >> 8;
  int h = (idx & 255) * 4;
  const float* base = dsout + (size_t)t * 4 * H_ + h;
  float4 a = *(const float4*)(base);
  float4 b = *(const float4*)(base + H_);
  float4 c = *(const float4*)(base + 2 * H_);
  float4 d = *(const float4*)(base + 3 * H_);
  float4 o;
  o.x = a.x + b.x + c.x + d.x;
  o.y = a.y + b.y + c.y + d.y;
  o.z = a.z + b.z + c.z + d.z;
  o.w = a.w + b.w + c.w + d.w;
  *(float4*)(routed + (size_t)t * H_ + h) = o;
}

// ---------------------------------------------------------------------------
extern "C" void kernel_launch(void* const* d_in, const int* in_sizes, int n_in,
                              void* d_out, int out_size, void* d_ws, size_t ws_size,
                              hipStream_t stream) {
  (void)in_sizes; (void)n_in; (void)out_size; (void)ws_size;
  const float* x    = (const float*)d_in[0];
  const float* gup  = (const float*)d_in[1];
  const float* gupb = (const float*)d_in[2];
  const float* dwn  = (const float*)d_in[3];
  const float* dwnb = (const float*)d_in[4];
  const float* rw   = (const float*)d_in[5];
  const float* rb   = (const float*)d_in[6];

  float* routed = (float*)d_out;
  float* scores = (float*)d_out + (size_t)T_ * H_;

  char* ws = (char*)d_ws;
  int*   counts   = (int*)ws;
  int*   tok_list = (int*)(ws + 256);
  float* w_list   = (float*)(ws + 256 + (size_t)E_ * T_ * 4);
  unsigned short* act = (unsigned short*)(ws + 256 + 2 * (size_t)E_ * T_ * 4);
  float* dsout = (float*)(ws + 256 + 2 * (size_t)E_ * T_ * 4
                          + (size_t)T_ * TOPK_ * I_ * 2);

  hipMemsetAsync(counts, 0, E_ * sizeof(int), stream);

  router_kernel<<<T_, 128, 0, stream>>>(x, rw, rb, scores, counts, tok_list, w_list);
  gateup_mfma<<<dim3(16, 32, 32), 256, 0, stream>>>(x, gup, gupb, counts, tok_list, act);
  down_mfma<<<dim3(8, 32, 32), 256, 0, stream>>>(act, dwn, dwnb, counts, tok_list, w_list, dsout);
  combine_kernel<<<(T_ * H_ / 4) / 256, 256, 0, stream>>>(dsout, routed);
}